// Round 7
// baseline (229.775 us; speedup 1.0000x reference)
//
#include <hip/hip_runtime.h>
#include <math.h>

#define BN_EPS 1e-5f

typedef short bf16x8 __attribute__((ext_vector_type(8)));
typedef float f32x4 __attribute__((ext_vector_type(4)));
typedef float f32x16 __attribute__((ext_vector_type(16)));
typedef unsigned short ushort8v __attribute__((ext_vector_type(8)));
typedef unsigned int uint;
typedef unsigned short ushort;

__device__ inline ushort f2bf(float f) {           // RNE float->bf16
    uint u = __float_as_uint(f);
    uint r = u + 0x7FFFu + ((u >> 16) & 1u);
    return (ushort)(r >> 16);
}
__device__ inline float bf2f(ushort u) { return __uint_as_float(((uint)u) << 16); }
__device__ inline uint cvtpk(float lo, float hi) { // packed 2xbf16 (RNE)
    uint r;
    asm("v_cvt_pk_bf16_f32 %0, %1, %2" : "=v"(r) : "v"(lo), "v"(hi));
    return r;
}

// ---------------------------------------------------------------------------
// Per-channel scale/shift for both BN layers: y = acc*sc + sh, then ReLU.
// ---------------------------------------------------------------------------
__global__ void scsh_kernel(const float* b1, const float* g1, const float* bb1,
                            const float* m1, const float* v1,
                            const float* b2, const float* g2, const float* bb2,
                            const float* m2, const float* v2,
                            float* scsh1, float* scsh2) {
    int t = threadIdx.x;
    if (t < 128) {
        float sc = g1[t] * rsqrtf(v1[t] + BN_EPS);
        scsh1[t] = sc;
        scsh1[128 + t] = (b1[t] - m1[t]) * sc + bb1[t];
    } else {
        int c = t - 128;
        float sc = g2[c] * rsqrtf(v2[c] + BN_EPS);
        scsh2[c] = sc;
        scsh2[128 + c] = (b2[c] - m2[c]) * sc + bb2[c];
    }
}

// ---------------------------------------------------------------------------
// x fp32 NCHW [16][64][128][128] -> xT bf16 16ci-planar [b][h][cc4][w][16]
// + fused pool partial sums (atomicAdd raw sums into pooled1).
// ---------------------------------------------------------------------------
__global__ void xprep_kernel(const float* __restrict__ x, ushort* __restrict__ xT,
                             float* __restrict__ pooled1) {
    __shared__ float t[64][65];
    const int b = blockIdx.y;
    const int p0 = blockIdx.x * 64;
    const int tid = threadIdx.x;
#pragma unroll
    for (int it = 0; it < 16; ++it) {
        const int idx = it * 256 + tid;
        const int ci = idx >> 6, p = idx & 63;
        t[ci][p] = x[((size_t)b * 64 + ci) * 16384 + p0 + p];
    }
    __syncthreads();
    const int h = p0 >> 7;
#pragma unroll
    for (int it = 0; it < 2; ++it) {
        const int p = it * 32 + (tid >> 3);
        const int w = (p0 & 127) + p;
        const int c0 = (tid & 7) * 8;
        const int cc = c0 >> 4;
        ushort8v u;
#pragma unroll
        for (int j = 0; j < 8; ++j) u[j] = f2bf(t[c0 + j][p]);
        *(ushort8v*)&xT[(((size_t)(b * 128 + h) * 4 + cc) * 128 + w) * 16 + (c0 & 15)] = u;
    }
    if (tid < 64) {
        float s = 0.f;
#pragma unroll 8
        for (int p = 0; p < 64; ++p) s += t[tid][p];
        atomicAdd(&pooled1[b * 64 + tid], s);
    }
}

// ---------------------------------------------------------------------------
// Routing (from raw pooled sums) + expert mix, writing wmix as the conv
// kernel's LDS weight image: per (b,cc16): 2304 granules of 16B,
// granule = (tap*128+co)*2 + (oct ^ ((co>>2)&1)), elems = 8 ci.
// ---------------------------------------------------------------------------
template <int CIN>
__global__ void mix_route_kernel(const float* __restrict__ w, const float* __restrict__ pooled,
                                 const float* __restrict__ fcw, const float* __restrict__ fcb,
                                 ushort* __restrict__ wmix) {
    constexpr int NCC = CIN / 16;
    __shared__ float rwl[48];
    const int tid = threadIdx.x;
    if (tid < 48) {
        const int bb = tid / 3, e = tid % 3;
        float d = 0.f;
        for (int c = 0; c < CIN; ++c) d += pooled[bb * CIN + c] * fcw[e * CIN + c];
        const float s = fcb[e] + d * (1.f / 16384.f);
        rwl[tid] = 1.f / (1.f + expf(-s));
    }
    __syncthreads();
    const int co = blockIdx.x;           // 0..127
    const int sw = (co >> 2) & 1;
    for (int b = 0; b < 16; ++b) {
        const float r0 = rwl[b * 3 + 0], r1 = rwl[b * 3 + 1], r2 = rwl[b * 3 + 2];
        for (int idx = tid; idx < CIN * 9; idx += 256) {
            const int ci = idx & (CIN - 1);
            const int tap = idx / CIN;
            const size_t off = ((size_t)co * CIN + ci) * 9 + tap;
            const float m = r0 * w[off]
                          + r1 * w[off + (size_t)128 * CIN * 9]
                          + r2 * w[off + (size_t)2 * 128 * CIN * 9];
            const int cc = ci >> 4, o = (ci >> 3) & 1, e = ci & 7;
            const size_t dst = (((size_t)(b * NCC + cc)) * 2304
                             + (tap * 128 + co) * 2 + (o ^ sw)) * 8 + e;
            wmix[dst] = f2bf(m);
        }
    }
}

// ---------------------------------------------------------------------------
// MFMA implicit-GEMM conv3x3(pad1) + fused bias/BN/ReLU. v7:
//  - R6 structure kept: 32x32x16 MFMA, tile M=128co x N=512px, 8 waves 2Mx4N,
//    dual-operand LDS dbuf, period-8 XOR octet swizzle on both operands
//  - staging addresses hoisted to ~8 per-thread regs; per-chunk stage is
//    ~25 VALU; no sched_barrier -> stage issues interleave with tap ds_reads
//  - s_setprio(1) around the tap loop (stage-issuing vs MFMA wave role split)
//  - conv1 epilogue: v_cvt_pk_bf16_f32 packing + FUSED pool2 reduction
//    (shfl_xor over 32 px-lanes + atomicAdd) -> pool2h kernel deleted
// ---------------------------------------------------------------------------
template <int CIN, bool TO_BF16>
__global__ __launch_bounds__(512, 2)
void conv_mfma6_kernel(const ushort* __restrict__ xT, const ushort* __restrict__ wmix,
                       const float* __restrict__ scsh,
                       float* __restrict__ outf, ushort* __restrict__ outh,
                       float* __restrict__ pool2) {
    constexpr int NCC = CIN / 16;
    constexpr int IBUF = 24960;          // 6 rows * 260 granules * 16B
    constexpr int WOFF = 2 * IBUF;       // 49920
    constexpr int WBUF = 36864;          // 2304 granules * 16B
    __shared__ __align__(16) char smem[123648];

    const int L = ((blockIdx.x & 7) << 6) | (blockIdx.x >> 3);  // 64 per XCD
    const int b = L >> 5;
    const int rt = L & 31;               // output rows rt*4 .. rt*4+3

    const int tid = threadIdx.x;
    const int lane = tid & 63, wid = tid >> 6;
    const int wm = wid >> 2, wn = wid & 3;       // 2(M) x 4(N=row)
    const int l31 = lane & 31, lhi = lane >> 5;

    f32x16 acc[2][4];
#pragma unroll
    for (int i = 0; i < 2; ++i)
#pragma unroll
        for (int j = 0; j < 4; ++j)
#pragma unroll
            for (int r = 0; r < 16; ++r) acc[i][j][r] = 0.f;

    const ushort* inb = xT + (size_t)b * 128 * NCC * 2048;
    const ushort* wmb = wmix + (size_t)b * NCC * 18432;

    // ---- hoisted staging state (computed once) ----
    // input slots u=0..2: slot j = wid + u*8; r = (wid>>2)+2u; i = wid&3
    const int iq   = (wid & 3) * 64 + lane;           // 0..511 within row
    const int icm  = iq >> 1;                          // image col 0..127
    const int iso  = (iq & 1) ^ (((icm + 1) >> 2) & 1);
    const int voff_in = icm * 16 + iso * 8;            // ushort offset in (row,cc)
    const int hg0     = rt * 4 - 1 + (wid >> 2);       // image row for u=0 (+2/u)
    const int dsti0   = ((wid >> 2) * 260 + 2 + (wid & 3) * 64) * 16;  // +8320/u
    // weight slots u=0..4: k = wid + u*8 (valid while k<36)
    const int wsoff  = wid * 512 + lane * 8;           // ushort, +4096/u
    const int wdst0  = WOFF + wid * 1024;              // byte,   +8192/u

    auto stage = [&](int bufi, int cc) {
        const int ccoff = cc * 2048;
#pragma unroll
        for (int u = 0; u < 3; ++u) {
            const int hg = hg0 + 2 * u;
            if ((unsigned)hg < 128u) {
                const ushort* src = inb + (size_t)hg * (NCC * 2048) + ccoff + voff_in;
                __builtin_amdgcn_global_load_lds(
                    (const __attribute__((address_space(1))) void*)src,
                    (__attribute__((address_space(3))) void*)(smem + bufi * IBUF + dsti0 + u * 8320),
                    16, 0, 0);
            }
        }
        const ushort* wsrc = wmb + (size_t)cc * 18432 + wsoff;
#pragma unroll
        for (int u = 0; u < 5; ++u) {
            if (wid + u * 8 < 36) {
                __builtin_amdgcn_global_load_lds(
                    (const __attribute__((address_space(1))) void*)(wsrc + u * 4096),
                    (__attribute__((address_space(3))) void*)(smem + bufi * WBUF + wdst0 + u * 8192),
                    16, 0, 0);
            }
        }
    };

    // ---- all 9 taps of a chunk: pure ds_read + MFMA ----
    auto taps = [&](int bufi) {
        const char* ldsI = smem + bufi * IBUF;
        const char* ldsW = smem + WOFF + bufi * WBUF;
        __builtin_amdgcn_s_setprio(1);
#pragma unroll
        for (int tap = 0; tap < 9; ++tap) {
            const int dy = tap / 3, dx = tap - dy * 3;
            bf16x8 af[2];
#pragma unroll
            for (int mf = 0; mf < 2; ++mf) {
                const int co = wm * 64 + mf * 32 + l31;
                const int g = (tap * 128 + co) * 2 + (lhi ^ ((co >> 2) & 1));
                af[mf] = *(const bf16x8*)(ldsW + g * 16);
            }
#pragma unroll
            for (int nf = 0; nf < 4; ++nf) {
                const int col = nf * 32 + l31 + dx;
                const int g = (wn + dy) * 260 + col * 2 + (lhi ^ ((col >> 2) & 1));
                const bf16x8 bv = *(const bf16x8*)(ldsI + g * 16);
#pragma unroll
                for (int mf = 0; mf < 2; ++mf)
                    acc[mf][nf] = __builtin_amdgcn_mfma_f32_32x32x16_bf16(
                        af[mf], bv, acc[mf][nf], 0, 0, 0);
            }
        }
        __builtin_amdgcn_s_setprio(0);
    };

    // ---- one-time zeroing: halo cols (0,129) all rows/bufs; OOB rows ----
    if (tid < 48) {
        const int bi = tid & 1, idx = tid >> 1;
        const int r = idx >> 2, e = idx & 3;
        const int rem = (e < 2) ? e : 256 + e;   // granules 0,1,258,259
        *(f32x4*)(smem + bi * IBUF + (r * 260 + rem) * 16) = f32x4{0.f, 0.f, 0.f, 0.f};
    }
    if (rt == 0 || rt == 31) {
        const int r = (rt == 0) ? 0 : 5;
        for (int g = tid; g < 520; g += 512) {
            const int bi = (g >= 260) ? 1 : 0, gr = g - bi * 260;
            *(f32x4*)(smem + bi * IBUF + (r * 260 + gr) * 16) = f32x4{0.f, 0.f, 0.f, 0.f};
        }
    }

    stage(0, 0);
    asm volatile("s_waitcnt vmcnt(0)" ::: "memory");
    __syncthreads();

    for (int cc = 0; cc < NCC; ++cc) {
        if (cc + 1 < NCC) stage((cc & 1) ^ 1, cc + 1);   // async; drains at barrier
        taps(cc & 1);                                    // pure LDS + MFMA
        __syncthreads();
    }

    // ---- epilogue: y = relu(acc*sc + sh) ----
    if constexpr (!TO_BF16) {
        // fp32 NCHW direct store: each (q,s,nf) = 32 consecutive floats/row
#pragma unroll
        for (int mf = 0; mf < 2; ++mf) {
            const int cob = wm * 64 + mf * 32 + 4 * lhi;
            f32x4 sc[4], sh[4];
#pragma unroll
            for (int q = 0; q < 4; ++q) {
                sc[q] = *(const f32x4*)&scsh[cob + 8 * q];
                sh[q] = *(const f32x4*)&scsh[128 + cob + 8 * q];
            }
#pragma unroll
            for (int nf = 0; nf < 4; ++nf) {
                const size_t pbase = (size_t)(rt * 4 + wn) * 128 + nf * 32 + l31;
#pragma unroll
                for (int q = 0; q < 4; ++q)
#pragma unroll
                    for (int s = 0; s < 4; ++s) {
                        float y = fmaf(acc[mf][nf][q * 4 + s], sc[q][s], sh[q][s]);
                        y = y > 0.f ? y : 0.f;
                        outf[((size_t)(b * 128 + cob + 8 * q + s)) * 16384 + pbase] = y;
                    }
            }
        }
    } else {
        // bf16 16ci-planar hT via padded-LDS transpose, 2 passes of 2 rows,
        // with FUSED pool2 per-channel reduction (fp32 y, pre-quantization)
        ushort* sf = (ushort*)smem;                      // [256 px][136]
#pragma unroll
        for (int p = 0; p < 2; ++p) {
            if ((wn >> 1) == p) {
                const int lr = wn & 1;
#pragma unroll
                for (int mf = 0; mf < 2; ++mf)
#pragma unroll
                    for (int q = 0; q < 4; ++q) {
                        const int co4 = wm * 64 + mf * 32 + 8 * q + 4 * lhi;
                        const f32x4 sc = *(const f32x4*)&scsh[co4];
                        const f32x4 sh = *(const f32x4*)&scsh[128 + co4];
                        float ps0 = 0.f, ps1 = 0.f, ps2 = 0.f, ps3 = 0.f;
#pragma unroll
                        for (int nf = 0; nf < 4; ++nf) {
                            const int px = lr * 128 + nf * 32 + l31;
                            float v[4];
#pragma unroll
                            for (int s = 0; s < 4; ++s) {
                                float y = fmaf(acc[mf][nf][q * 4 + s], sc[s], sh[s]);
                                v[s] = y > 0.f ? y : 0.f;
                            }
                            ps0 += v[0]; ps1 += v[1]; ps2 += v[2]; ps3 += v[3];
                            uint2 pk;
                            pk.x = cvtpk(v[0], v[1]);
                            pk.y = cvtpk(v[2], v[3]);
                            *(uint2*)&sf[px * 136 + co4] = pk;
                        }
#pragma unroll
                        for (int m = 1; m <= 16; m <<= 1) {
                            ps0 += __shfl_xor(ps0, m);
                            ps1 += __shfl_xor(ps1, m);
                            ps2 += __shfl_xor(ps2, m);
                            ps3 += __shfl_xor(ps3, m);
                        }
                        if (l31 == 0) {
                            atomicAdd(&pool2[b * 128 + co4 + 0], ps0);
                            atomicAdd(&pool2[b * 128 + co4 + 1], ps1);
                            atomicAdd(&pool2[b * 128 + co4 + 2], ps2);
                            atomicAdd(&pool2[b * 128 + co4 + 3], ps3);
                        }
                    }
            }
            __syncthreads();
#pragma unroll
            for (int it = 0; it < 4; ++it) {
                const int id = it * 512 + tid;           // [lr2][cc8][w128]
                const int lr = id >> 10, cc = (id >> 7) & 7, w = id & 127;
                const uint4 v0 = *(const uint4*)&sf[(lr * 128 + w) * 136 + cc * 16];
                const uint4 v1 = *(const uint4*)&sf[(lr * 128 + w) * 136 + cc * 16 + 8];
                ushort* dst = outh + (((size_t)(b * 128 + rt * 4 + 2 * p + lr)) * 8 + cc) * 2048 + w * 16;
                *(uint4*)dst = v0;
                *(uint4*)(dst + 8) = v1;
            }
            if (p == 0) __syncthreads();
        }
    }
}

// ---------------------------------------------------------------------------
extern "C" void kernel_launch(void* const* d_in, const int* in_sizes, int n_in,
                              void* d_out, int out_size, void* d_ws, size_t ws_size,
                              hipStream_t stream) {
    const float* x     = (const float*)d_in[0];
    const float* w1    = (const float*)d_in[1];
    const float* b1    = (const float*)d_in[2];
    const float* fc1_w = (const float*)d_in[3];
    const float* fc1_b = (const float*)d_in[4];
    const float* bn1g  = (const float*)d_in[5];
    const float* bn1b  = (const float*)d_in[6];
    const float* bn1m  = (const float*)d_in[7];
    const float* bn1v  = (const float*)d_in[8];
    const float* w2    = (const float*)d_in[9];
    const float* b2    = (const float*)d_in[10];
    const float* fc2_w = (const float*)d_in[11];
    const float* fc2_b = (const float*)d_in[12];
    const float* bn2g  = (const float*)d_in[13];
    const float* bn2b  = (const float*)d_in[14];
    const float* bn2m  = (const float*)d_in[15];
    const float* bn2v  = (const float*)d_in[16];

    float* out = (float*)d_out;
    char* ws = (char*)d_ws;

    // workspace layout (bytes)
    ushort* hT    = (ushort*)(ws + 0);            //  67,108,864
    ushort* xT    = (ushort*)(ws + 67108864);     //  33,554,432
    ushort* wmix1 = (ushort*)(ws + 100663296);    //   2,359,296
    ushort* wmix2 = (ushort*)(ws + 103022592);    //   4,718,592
    float*  pool1 = (float*) (ws + 107741184);    //       4,096
    float*  pool2 = (float*) (ws + 107745280);    //       8,192
    float*  scsh1 = (float*) (ws + 107753472);    //       1,024
    float*  scsh2 = (float*) (ws + 107754496);    //       1,024

    hipMemsetAsync(pool1, 0, 4096, stream);
    hipMemsetAsync(pool2, 0, 8192, stream);

    scsh_kernel<<<1, 256, 0, stream>>>(b1, bn1g, bn1b, bn1m, bn1v,
                                       b2, bn2g, bn2b, bn2m, bn2v, scsh1, scsh2);

    // ---- layer 1 ----
    xprep_kernel<<<dim3(256, 16), 256, 0, stream>>>(x, xT, pool1);
    mix_route_kernel<64><<<128, 256, 0, stream>>>(w1, pool1, fc1_w, fc1_b, wmix1);
    conv_mfma6_kernel<64, true><<<512, 512, 0, stream>>>(
        xT, wmix1, scsh1, nullptr, hT, pool2);

    // ---- layer 2 ----
    mix_route_kernel<128><<<128, 256, 0, stream>>>(w2, pool2, fc2_w, fc2_b, wmix2);
    conv_mfma6_kernel<128, false><<<512, 512, 0, stream>>>(
        hT, wmix2, scsh2, out, nullptr, nullptr);
}

// Round 8
// 198.542 us; speedup vs baseline: 1.1573x; 1.1573x over previous
//
#include <hip/hip_runtime.h>
#include <math.h>

#define BN_EPS 1e-5f

typedef short bf16x8 __attribute__((ext_vector_type(8)));
typedef float f32x4 __attribute__((ext_vector_type(4)));
typedef float f32x16 __attribute__((ext_vector_type(16)));
typedef unsigned short ushort8v __attribute__((ext_vector_type(8)));
typedef unsigned int uint;
typedef unsigned short ushort;

__device__ inline ushort f2bf(float f) {           // RNE float->bf16
    uint u = __float_as_uint(f);
    uint r = u + 0x7FFFu + ((u >> 16) & 1u);
    return (ushort)(r >> 16);
}
__device__ inline float bf2f(ushort u) { return __uint_as_float(((uint)u) << 16); }
__device__ inline uint cvtpk(float lo, float hi) { // packed 2xbf16 (RNE)
    uint r;
    asm("v_cvt_pk_bf16_f32 %0, %1, %2" : "=v"(r) : "v"(lo), "v"(hi));
    return r;
}

// ---------------------------------------------------------------------------
// Per-channel scale/shift for both BN layers: y = acc*sc + sh, then ReLU.
// ---------------------------------------------------------------------------
__global__ void scsh_kernel(const float* b1, const float* g1, const float* bb1,
                            const float* m1, const float* v1,
                            const float* b2, const float* g2, const float* bb2,
                            const float* m2, const float* v2,
                            float* scsh1, float* scsh2) {
    int t = threadIdx.x;
    if (t < 128) {
        float sc = g1[t] * rsqrtf(v1[t] + BN_EPS);
        scsh1[t] = sc;
        scsh1[128 + t] = (b1[t] - m1[t]) * sc + bb1[t];
    } else {
        int c = t - 128;
        float sc = g2[c] * rsqrtf(v2[c] + BN_EPS);
        scsh2[c] = sc;
        scsh2[128 + c] = (b2[c] - m2[c]) * sc + bb2[c];
    }
}

// ---------------------------------------------------------------------------
// x fp32 NCHW [16][64][128][128] -> xT bf16 16ci-planar [b][h][cc4][w][16]
// + fused pool partial sums (atomicAdd raw sums into pooled1).
// ---------------------------------------------------------------------------
__global__ void xprep_kernel(const float* __restrict__ x, ushort* __restrict__ xT,
                             float* __restrict__ pooled1) {
    __shared__ float t[64][65];
    const int b = blockIdx.y;
    const int p0 = blockIdx.x * 64;
    const int tid = threadIdx.x;
#pragma unroll
    for (int it = 0; it < 16; ++it) {
        const int idx = it * 256 + tid;
        const int ci = idx >> 6, p = idx & 63;
        t[ci][p] = x[((size_t)b * 64 + ci) * 16384 + p0 + p];
    }
    __syncthreads();
    const int h = p0 >> 7;
#pragma unroll
    for (int it = 0; it < 2; ++it) {
        const int p = it * 32 + (tid >> 3);
        const int w = (p0 & 127) + p;
        const int c0 = (tid & 7) * 8;
        const int cc = c0 >> 4;
        ushort8v u;
#pragma unroll
        for (int j = 0; j < 8; ++j) u[j] = f2bf(t[c0 + j][p]);
        *(ushort8v*)&xT[(((size_t)(b * 128 + h) * 4 + cc) * 128 + w) * 16 + (c0 & 15)] = u;
    }
    if (tid < 64) {
        float s = 0.f;
#pragma unroll 8
        for (int p = 0; p < 64; ++p) s += t[tid][p];
        atomicAdd(&pooled1[b * 64 + tid], s);
    }
}

// ---------------------------------------------------------------------------
// Pool hT (bf16 16ci-planar [b][h][cc8][w][16]) -> pooled2 raw sums (atomic).
// ---------------------------------------------------------------------------
__global__ void pool2h_kernel(const ushort* __restrict__ hT, float* __restrict__ pooled2) {
    const int b = blockIdx.x, slab = blockIdx.y;
    const int tid = threadIdx.x;                  // 256
    const int cc = tid >> 5, o = (tid >> 4) & 1, wb = tid & 15;
    float a[8] = {0.f, 0.f, 0.f, 0.f, 0.f, 0.f, 0.f, 0.f};
    for (int r = 0; r < 4; ++r) {
        const int h = slab * 4 + r;
        const ushort* base = hT + ((size_t)(b * 128 + h) * 8 + cc) * 2048 + o * 8;
#pragma unroll
        for (int k = 0; k < 8; ++k) {
            const ushort8v u = *(const ushort8v*)(base + (wb + k * 16) * 16);
#pragma unroll
            for (int j = 0; j < 8; ++j) a[j] += bf2f(u[j]);
        }
    }
    __shared__ float sp[16][8][17];
    const int grp0 = cc * 2 + o;
#pragma unroll
    for (int j = 0; j < 8; ++j) sp[grp0][j][wb] = a[j];
    __syncthreads();
    if (tid < 128) {
        const int grp = tid >> 3, j = tid & 7;
        float s = 0.f;
#pragma unroll
        for (int k = 0; k < 16; ++k) s += sp[grp][j][k];
        const int c = (grp >> 1) * 16 + (grp & 1) * 8 + j;
        atomicAdd(&pooled2[b * 128 + c], s);
    }
}

// ---------------------------------------------------------------------------
// Routing (from raw pooled sums) + expert mix, writing wmix as the conv
// kernel's LDS weight image: per (b,cc16): 2304 granules of 16B,
// granule = (tap*128+co)*2 + (oct ^ ((co>>2)&1)), elems = 8 ci.
// ---------------------------------------------------------------------------
template <int CIN>
__global__ void mix_route_kernel(const float* __restrict__ w, const float* __restrict__ pooled,
                                 const float* __restrict__ fcw, const float* __restrict__ fcb,
                                 ushort* __restrict__ wmix) {
    constexpr int NCC = CIN / 16;
    __shared__ float rwl[48];
    const int tid = threadIdx.x;
    if (tid < 48) {
        const int bb = tid / 3, e = tid % 3;
        float d = 0.f;
        for (int c = 0; c < CIN; ++c) d += pooled[bb * CIN + c] * fcw[e * CIN + c];
        const float s = fcb[e] + d * (1.f / 16384.f);
        rwl[tid] = 1.f / (1.f + expf(-s));
    }
    __syncthreads();
    const int co = blockIdx.x;           // 0..127
    const int sw = (co >> 2) & 1;
    for (int b = 0; b < 16; ++b) {
        const float r0 = rwl[b * 3 + 0], r1 = rwl[b * 3 + 1], r2 = rwl[b * 3 + 2];
        for (int idx = tid; idx < CIN * 9; idx += 256) {
            const int ci = idx & (CIN - 1);
            const int tap = idx / CIN;
            const size_t off = ((size_t)co * CIN + ci) * 9 + tap;
            const float m = r0 * w[off]
                          + r1 * w[off + (size_t)128 * CIN * 9]
                          + r2 * w[off + (size_t)2 * 128 * CIN * 9];
            const int cc = ci >> 4, o = (ci >> 3) & 1, e = ci & 7;
            const size_t dst = (((size_t)(b * NCC + cc)) * 2304
                             + (tap * 128 + co) * 2 + (o ^ sw)) * 8 + e;
            wmix[dst] = f2bf(m);
        }
    }
}

// ---------------------------------------------------------------------------
// MFMA implicit-GEMM conv3x3(pad1) + fused bias/BN/ReLU. v8:
//  - 4-wave blocks (256 thr), wave tile 128co x 64px (4mf x 2nf),
//    block tile 128co x 256px (2 rows) -> acc 128 AGPR, ~100 VGPR
//  - LDS 70,144B: input dbuf 2x16,640 + weight SINGLE buffer 36,864
//    -> TWO co-resident blocks/CU (reg cap 2 waves/SIMD matches 8 waves/CU);
//    partner block hides each block's stage drains
//  - per chunk: stage_I(next) async -> sched_barrier -> taps (pure LDS+MFMA)
//    -> barrier -> stage_W(next) -> barrier
//  - period-8 XOR octet swizzle on both operands (pre-swizzled global src)
// ---------------------------------------------------------------------------
template <int CIN, bool TO_BF16>
__global__ __launch_bounds__(256, 2)
void conv_mfma7_kernel(const ushort* __restrict__ xT, const ushort* __restrict__ wmix,
                       const float* __restrict__ scsh,
                       float* __restrict__ outf, ushort* __restrict__ outh) {
    constexpr int NCC = CIN / 16;
    constexpr int IBUF = 16640;          // 4 rows * 260 granules * 16B
    constexpr int WOFF = 2 * IBUF;       // 33280
    __shared__ __align__(16) char smem[70144];

    const int L = ((blockIdx.x & 7) << 7) | (blockIdx.x >> 3);  // 128/XCD = 2 images
    const int b = L >> 6;
    const int rt = L & 63;               // output rows rt*2, rt*2+1

    const int tid = threadIdx.x;
    const int lane = tid & 63, wid = tid >> 6;   // 4 waves
    const int l31 = lane & 31, lhi = lane >> 5;
    const int wrow = wid >> 1, wcol = (wid & 1) * 64;  // wave's px region

    f32x16 acc[4][2];
#pragma unroll
    for (int i = 0; i < 4; ++i)
#pragma unroll
        for (int j = 0; j < 2; ++j)
#pragma unroll
            for (int r = 0; r < 16; ++r) acc[i][j][r] = 0.f;

    const ushort* inb = xT + (size_t)b * 128 * NCC * 2048;
    const ushort* wmb = wmix + (size_t)b * NCC * 18432;

    // ---- hoisted staging state ----
    // input: per u=0..3 one slot: row r=u, cols [wid*32, wid*32+32)
    const int iq   = wid * 64 + lane;                 // 0..255
    const int icm  = iq >> 1;                          // image col 0..127
    const int iso  = (iq & 1) ^ (((icm + 1) >> 2) & 1);
    const int voff_in = icm * 16 + iso * 8;            // ushort offset within (row,cc)
    const int hg0  = rt * 2 - 1;                       // image row for r=0
    const int dsti0 = (2 + iq) * 16;                   // byte within row granules
    // weights: per u=0..8 slot j=wid+4u
    const int wsoff = wid * 512 + lane * 8;            // ushort, +2048/u
    const int wdst0 = WOFF + wid * 1024 + lane * 16;   // byte,   +4096/u

    auto stage_I = [&](int bufi, int cc) {
        const int ccoff = cc * 2048;
#pragma unroll
        for (int u = 0; u < 4; ++u) {
            const int hg = hg0 + u;
            if ((unsigned)hg < 128u) {
                const ushort* src = inb + (size_t)hg * (NCC * 2048) + ccoff + voff_in;
                __builtin_amdgcn_global_load_lds(
                    (const __attribute__((address_space(1))) void*)src,
                    (__attribute__((address_space(3))) void*)(smem + bufi * IBUF + u * 4160 + dsti0),
                    16, 0, 0);
            }
        }
    };
    auto stage_W = [&](int cc) {
        const ushort* wsrc = wmb + (size_t)cc * 18432 + wsoff;
#pragma unroll
        for (int u = 0; u < 9; ++u) {
            __builtin_amdgcn_global_load_lds(
                (const __attribute__((address_space(1))) void*)(wsrc + u * 2048),
                (__attribute__((address_space(3))) void*)(smem + wdst0 + u * 4096),
                16, 0, 0);
        }
    };

    // ---- all 9 taps of a chunk: pure ds_read + MFMA ----
    auto taps = [&](int bufi) {
        const char* ldsI = smem + bufi * IBUF;
        const char* ldsW = smem + WOFF;
#pragma unroll
        for (int tap = 0; tap < 9; ++tap) {
            const int dy = tap / 3, dx = tap - dy * 3;
            bf16x8 af[4];
#pragma unroll
            for (int mf = 0; mf < 4; ++mf) {
                const int co = mf * 32 + l31;
                const int g = (tap * 128 + co) * 2 + (lhi ^ ((co >> 2) & 1));
                af[mf] = *(const bf16x8*)(ldsW + g * 16);
            }
#pragma unroll
            for (int nf = 0; nf < 2; ++nf) {
                const int colp = wcol + nf * 32 + l31 + dx;
                const int g = (wrow + dy) * 260 + colp * 2 + (lhi ^ ((colp >> 2) & 1));
                const bf16x8 bv = *(const bf16x8*)(ldsI + g * 16);
#pragma unroll
                for (int mf = 0; mf < 4; ++mf)
                    acc[mf][nf] = __builtin_amdgcn_mfma_f32_32x32x16_bf16(
                        af[mf], bv, acc[mf][nf], 0, 0, 0);
            }
        }
    };

    // ---- one-time zeroing: halo cols (granule cols 0,129) rows 0..3, both bufs ----
    if (tid < 32) {
        const int bi = tid >> 4, idx = tid & 15;
        const int r = idx >> 2, e = idx & 3;
        const int rem = (e < 2) ? e : 256 + e;   // granules 0,1,258,259
        *(f32x4*)(smem + bi * IBUF + (r * 260 + rem) * 16) = f32x4{0.f, 0.f, 0.f, 0.f};
    }
    if (rt == 0 || rt == 63) {
        const int r = (rt == 0) ? 0 : 3;
        for (int g = tid; g < 520; g += 256) {
            const int bi = (g >= 260) ? 1 : 0, gr = g - bi * 260;
            *(f32x4*)(smem + bi * IBUF + (r * 260 + gr) * 16) = f32x4{0.f, 0.f, 0.f, 0.f};
        }
    }

    stage_W(0);
    stage_I(0, 0);
    asm volatile("s_waitcnt vmcnt(0)" ::: "memory");
    __syncthreads();

    for (int cc = 0; cc < NCC; ++cc) {
        if (cc + 1 < NCC) stage_I((cc & 1) ^ 1, cc + 1);   // async
        __builtin_amdgcn_sched_barrier(0);
        taps(cc & 1);                                      // pure LDS + MFMA
        __syncthreads();                                   // drains I(next); W free
        if (cc + 1 < NCC) {
            stage_W(cc + 1);
            __syncthreads();                               // drains W(next)
        }
    }

    // ---- epilogue: y = relu(acc*sc + sh) ----
    if constexpr (!TO_BF16) {
        // fp32 NCHW direct: each (mf,q,s,nf) = 32 consecutive floats of a row
#pragma unroll
        for (int mf = 0; mf < 4; ++mf) {
            const int cob = mf * 32 + 4 * lhi;
            f32x4 sc[4], sh[4];
#pragma unroll
            for (int q = 0; q < 4; ++q) {
                sc[q] = *(const f32x4*)&scsh[cob + 8 * q];
                sh[q] = *(const f32x4*)&scsh[128 + cob + 8 * q];
            }
#pragma unroll
            for (int nf = 0; nf < 2; ++nf) {
                const size_t pbase = (size_t)(rt * 2 + wrow) * 128 + wcol + nf * 32 + l31;
#pragma unroll
                for (int q = 0; q < 4; ++q)
#pragma unroll
                    for (int s = 0; s < 4; ++s) {
                        float y = fmaf(acc[mf][nf][q * 4 + s], sc[q][s], sh[q][s]);
                        y = y > 0.f ? y : 0.f;
                        outf[((size_t)(b * 128 + cob + 8 * q + s)) * 16384 + pbase] = y;
                    }
            }
        }
    } else {
        // bf16 16ci-planar hT via padded-LDS transpose (single pass: block=256px)
        ushort* sf = (ushort*)smem;                      // [256 px][136]
#pragma unroll
        for (int mf = 0; mf < 4; ++mf)
#pragma unroll
            for (int q = 0; q < 4; ++q) {
                const int co4 = mf * 32 + 8 * q + 4 * lhi;
                const f32x4 sc = *(const f32x4*)&scsh[co4];
                const f32x4 sh = *(const f32x4*)&scsh[128 + co4];
#pragma unroll
                for (int nf = 0; nf < 2; ++nf) {
                    const int px = wrow * 128 + wcol + nf * 32 + l31;
                    float v[4];
#pragma unroll
                    for (int s = 0; s < 4; ++s) {
                        float y = fmaf(acc[mf][nf][q * 4 + s], sc[s], sh[s]);
                        v[s] = y > 0.f ? y : 0.f;
                    }
                    uint2 pk;
                    pk.x = cvtpk(v[0], v[1]);
                    pk.y = cvtpk(v[2], v[3]);
                    *(uint2*)&sf[px * 136 + co4] = pk;
                }
            }
        __syncthreads();
#pragma unroll
        for (int it = 0; it < 8; ++it) {
            const int id = it * 256 + tid;               // [lr2][cc8][w128]
            const int lr = id >> 10, cc = (id >> 7) & 7, w = id & 127;
            const uint4 v0 = *(const uint4*)&sf[(lr * 128 + w) * 136 + cc * 16];
            const uint4 v1 = *(const uint4*)&sf[(lr * 128 + w) * 136 + cc * 16 + 8];
            ushort* dst = outh + (((size_t)(b * 128 + rt * 2 + lr)) * 8 + cc) * 2048 + w * 16;
            *(uint4*)dst = v0;
            *(uint4*)(dst + 8) = v1;
        }
    }
}

// ---------------------------------------------------------------------------
extern "C" void kernel_launch(void* const* d_in, const int* in_sizes, int n_in,
                              void* d_out, int out_size, void* d_ws, size_t ws_size,
                              hipStream_t stream) {
    const float* x     = (const float*)d_in[0];
    const float* w1    = (const float*)d_in[1];
    const float* b1    = (const float*)d_in[2];
    const float* fc1_w = (const float*)d_in[3];
    const float* fc1_b = (const float*)d_in[4];
    const float* bn1g  = (const float*)d_in[5];
    const float* bn1b  = (const float*)d_in[6];
    const float* bn1m  = (const float*)d_in[7];
    const float* bn1v  = (const float*)d_in[8];
    const float* w2    = (const float*)d_in[9];
    const float* b2    = (const float*)d_in[10];
    const float* fc2_w = (const float*)d_in[11];
    const float* fc2_b = (const float*)d_in[12];
    const float* bn2g  = (const float*)d_in[13];
    const float* bn2b  = (const float*)d_in[14];
    const float* bn2m  = (const float*)d_in[15];
    const float* bn2v  = (const float*)d_in[16];

    float* out = (float*)d_out;
    char* ws = (char*)d_ws;

    // workspace layout (bytes)
    ushort* hT    = (ushort*)(ws + 0);            //  67,108,864
    ushort* xT    = (ushort*)(ws + 67108864);     //  33,554,432
    ushort* wmix1 = (ushort*)(ws + 100663296);    //   2,359,296
    ushort* wmix2 = (ushort*)(ws + 103022592);    //   4,718,592
    float*  pool1 = (float*) (ws + 107741184);    //       4,096
    float*  pool2 = (float*) (ws + 107745280);    //       8,192
    float*  scsh1 = (float*) (ws + 107753472);    //       1,024
    float*  scsh2 = (float*) (ws + 107754496);    //       1,024

    hipMemsetAsync(pool1, 0, 4096, stream);
    hipMemsetAsync(pool2, 0, 8192, stream);

    scsh_kernel<<<1, 256, 0, stream>>>(b1, bn1g, bn1b, bn1m, bn1v,
                                       b2, bn2g, bn2b, bn2m, bn2v, scsh1, scsh2);

    // ---- layer 1 ----
    xprep_kernel<<<dim3(256, 16), 256, 0, stream>>>(x, xT, pool1);
    mix_route_kernel<64><<<128, 256, 0, stream>>>(w1, pool1, fc1_w, fc1_b, wmix1);
    conv_mfma7_kernel<64, true><<<1024, 256, 0, stream>>>(
        xT, wmix1, scsh1, nullptr, hT);

    // ---- layer 2 ----
    pool2h_kernel<<<dim3(16, 32), 256, 0, stream>>>(hT, pool2);
    mix_route_kernel<128><<<128, 256, 0, stream>>>(w2, pool2, fc2_w, fc2_b, wmix2);
    conv_mfma7_kernel<128, false><<<1024, 256, 0, stream>>>(
        hT, wmix2, scsh2, out, nullptr);
}